// Round 1
// baseline (416.452 us; speedup 1.0000x reference)
//
#include <hip/hip_runtime.h>

// NonLocalAggregation on MI355X.
// Sizes fixed by setup_inputs(): b=32, f=64, h=w=32 (n=1024), out=64, k=8.
// Workspace layout (needs ~9.2 MB):
//   xt  : [32][1024][64] fp32 transposed features
//   sq  : [32][1024]     fp32 squared norms
//   nbr : [32][1024][8]  int  neighbor indices
#define BATCH 32
#define FDIM  64
#define NPT   1024
#define KNN   8
#define OCH   64
#define INFF  3.402823466e+38f

// ---------------- kernel 1: transpose + squared norms ----------------
__global__ __launch_bounds__(256) void k_prep(const float* __restrict__ x,
                                              float* __restrict__ xt,
                                              float* __restrict__ sq) {
  __shared__ float t[64][65];  // [f][n_local], pad 65 -> conflict-free both ways
  const int bid = blockIdx.x;
  const int b   = bid >> 4;
  const int n0  = (bid & 15) << 6;
  const int tid = threadIdx.x;
  const int nl  = tid & 63;
  const int f0  = tid >> 6;
  const float* xb = x + (size_t)b * FDIM * NPT;
#pragma unroll
  for (int i = 0; i < 16; ++i) {
    const int f = f0 * 16 + i;
    t[f][nl] = xb[f * NPT + n0 + nl];          // coalesced over nl
  }
  __syncthreads();
  const int fl = tid & 63;
  const int g0 = tid >> 6;
  float* xtb = xt + ((size_t)b * NPT + n0) * FDIM;
#pragma unroll
  for (int i = 0; i < 16; ++i) {
    const int nn = g0 * 16 + i;
    xtb[nn * FDIM + fl] = t[fl][nn];           // coalesced over fl
  }
  if (tid < 64) {
    float s = 0.f;
#pragma unroll
    for (int f = 0; f < 64; ++f) s = fmaf(t[f][tid], t[f][tid], s);
    sq[b * NPT + n0 + tid] = s;
  }
}

// ---------------- kernel 2: pairwise distances + top-8 ----------------
// Block: 256 threads = 64 rows x 4 column-chunks. 512 blocks (b, row-tile).
// Score = sq[m] - 2*dot(p, x_m)  (row-constant sq[r] dropped: ordering invariant).
__global__ __launch_bounds__(256, 2) void k_knn(const float* __restrict__ xt,
                                                const float* __restrict__ sq,
                                                int* __restrict__ nbr) {
  __shared__ float tile[64 * 64];   // 64 columns x 64 features, linear copy
  __shared__ float sqt[64];
  __shared__ float cand_d[64][33];  // pad 33 -> conflict-free (r+c)%32
  __shared__ int   cand_i[64][33];

  const int bid = blockIdx.x;
  const int b   = bid >> 4;
  const int r0  = (bid & 15) << 6;
  const int tid = threadIdx.x;
  const int l   = tid & 63;   // row lane
  const int w   = tid >> 6;   // column chunk (wave id, uniform per wave)

  // own row features -> 64 VGPRs
  float4 pr[16];
  {
    const float4* prow = (const float4*)(xt + ((size_t)b * NPT + r0 + l) * FDIM);
#pragma unroll
    for (int q = 0; q < 16; ++q) pr[q] = prow[q];
  }

  float d8[8]; int i8[8];
#pragma unroll
  for (int s = 0; s < 8; ++s) { d8[s] = INFF; i8[s] = 0; }
  float wd = INFF;  // current worst (max) of kept 8

  // tie-safe evict-max insert: replace FIRST slot whose value == wd
  auto ins = [&](float sc, int idx) {
    if (sc < wd) {
      bool done = false;
#pragma unroll
      for (int s = 0; s < 8; ++s) {
        const bool hit = (!done) && (d8[s] == wd);
        d8[s] = hit ? sc  : d8[s];
        i8[s] = hit ? idx : i8[s];
        done = done || hit;
      }
      const float m01 = fmaxf(d8[0], d8[1]), m23 = fmaxf(d8[2], d8[3]);
      const float m45 = fmaxf(d8[4], d8[5]), m67 = fmaxf(d8[6], d8[7]);
      wd = fmaxf(fmaxf(m01, m23), fmaxf(m45, m67));
    }
  };

  for (int ct = 0; ct < 16; ++ct) {
    const int c0 = ct * 64;
    {  // stage 16 KB column tile (contiguous in xt) + norms
      const float4* src = (const float4*)(xt + ((size_t)b * NPT + c0) * FDIM);
      float4* dst = (float4*)tile;
#pragma unroll
      for (int q = 0; q < 4; ++q) dst[tid + q * 256] = src[tid + q * 256];
      if (tid < 64) sqt[tid] = sq[b * NPT + c0 + tid];
    }
    __syncthreads();

    for (int mm0 = 0; mm0 < 16; mm0 += 4) {
      const int mc = 16 * w + mm0;  // wave-uniform -> broadcast LDS reads
      const float4* t0 = (const float4*)(tile + (mc + 0) * 64);
      const float4* t1 = (const float4*)(tile + (mc + 1) * 64);
      const float4* t2 = (const float4*)(tile + (mc + 2) * 64);
      const float4* t3 = (const float4*)(tile + (mc + 3) * 64);
      float a0 = 0.f, a1 = 0.f, a2 = 0.f, a3 = 0.f;
#pragma unroll
      for (int q = 0; q < 16; ++q) {
        const float4 pv = pr[q];
        const float4 v0 = t0[q], v1 = t1[q], v2 = t2[q], v3 = t3[q];
        a0 = fmaf(pv.x, v0.x, fmaf(pv.y, v0.y, fmaf(pv.z, v0.z, fmaf(pv.w, v0.w, a0))));
        a1 = fmaf(pv.x, v1.x, fmaf(pv.y, v1.y, fmaf(pv.z, v1.z, fmaf(pv.w, v1.w, a1))));
        a2 = fmaf(pv.x, v2.x, fmaf(pv.y, v2.y, fmaf(pv.z, v2.z, fmaf(pv.w, v2.w, a2))));
        a3 = fmaf(pv.x, v3.x, fmaf(pv.y, v3.y, fmaf(pv.z, v3.z, fmaf(pv.w, v3.w, a3))));
      }
      const float s0 = fmaf(-2.f, a0, sqt[mc + 0]);
      const float s1 = fmaf(-2.f, a1, sqt[mc + 1]);
      const float s2 = fmaf(-2.f, a2, sqt[mc + 2]);
      const float s3 = fmaf(-2.f, a3, sqt[mc + 3]);
      const int mg = c0 + mc;
      ins(s0, mg + 0); ins(s1, mg + 1); ins(s2, mg + 2); ins(s3, mg + 3);
    }
    __syncthreads();
  }

  // publish per-chunk top-8, then merge 32 candidates/row (low-index tie-break)
#pragma unroll
  for (int s = 0; s < 8; ++s) {
    cand_d[l][w * 8 + s] = d8[s];
    cand_i[l][w * 8 + s] = i8[s];
  }
  __syncthreads();

  if (tid < 64) {
    const int r = tid;
    int* outp = nbr + ((size_t)b * NPT + r0 + r) * KNN;
#pragma unroll 1
    for (int s = 0; s < 8; ++s) {
      float bd = cand_d[r][0]; int bi = cand_i[r][0]; int bslot = 0;
#pragma unroll 1
      for (int c = 1; c < 32; ++c) {
        const float cd = cand_d[r][c];
        const int   ci = cand_i[r][c];
        if ((cd < bd) || ((cd == bd) && (ci < bi))) { bd = cd; bi = ci; bslot = c; }
      }
      cand_d[r][bslot] = INFF;
      outp[s] = bi;
    }
  }
}

// ---------------- kernel 3: gather + fused dual matvec ----------------
// out[b,o,n] = Wd·(mean8(nbr)-xf) + Ws·xf + (bd+bs+bias)
__global__ __launch_bounds__(256, 2) void k_out(const float* __restrict__ xt,
                                                const int* __restrict__ nbr,
                                                const float* __restrict__ Wd,
                                                const float* __restrict__ bdv,
                                                const float* __restrict__ Ws,
                                                const float* __restrict__ bsv,
                                                const float* __restrict__ bias,
                                                float* __restrict__ out) {
  __shared__ float wtd[64][68];  // W^T [f][o], pad 68 keeps 16B align, 8-way max once
  __shared__ float wts[64][68];
  __shared__ float mdt[64][65];  // meanDiff^T [f][r]
  __shared__ float xrt[64][65];  // xf^T       [f][r]
  __shared__ float cb[64];

  const int bid = blockIdx.x;
  const int b   = bid >> 4;
  const int r0  = (bid & 15) << 6;
  const int tid = threadIdx.x;

  {  // stage weights transposed (coalesced global reads over f)
    const int fl = tid & 63, og = tid >> 6;
#pragma unroll
    for (int i = 0; i < 16; ++i) {
      const int o = og * 16 + i;
      wtd[fl][o] = Wd[o * 64 + fl];
      wts[fl][o] = Ws[o * 64 + fl];
    }
    if (tid < 64) cb[tid] = bdv[tid] + bsv[tid] + bias[tid];
  }

  {  // gather: thread (r, c) owns f-segment [16c,16c+16) of row r0+r
    const int r = tid & 63, c = tid >> 6;
    const int row = r0 + r;
    const int* np = nbr + ((size_t)b * NPT + row) * KNN;
    float s[16];
#pragma unroll
    for (int q = 0; q < 16; ++q) s[q] = 0.f;
    for (int s8 = 0; s8 < 8; ++s8) {
      const int j = np[s8];
      const float4* nv = (const float4*)(xt + ((size_t)b * NPT + j) * FDIM + c * 16);
#pragma unroll
      for (int q = 0; q < 4; ++q) {
        const float4 v = nv[q];
        s[q * 4 + 0] += v.x; s[q * 4 + 1] += v.y;
        s[q * 4 + 2] += v.z; s[q * 4 + 3] += v.w;
      }
    }
    const float4* xv4 = (const float4*)(xt + ((size_t)b * NPT + row) * FDIM + c * 16);
#pragma unroll
    for (int q = 0; q < 4; ++q) {
      const float4 xv = xv4[q];
      const int f = c * 16 + q * 4;
      mdt[f + 0][r] = fmaf(s[q * 4 + 0], 0.125f, -xv.x);
      mdt[f + 1][r] = fmaf(s[q * 4 + 1], 0.125f, -xv.y);
      mdt[f + 2][r] = fmaf(s[q * 4 + 2], 0.125f, -xv.z);
      mdt[f + 3][r] = fmaf(s[q * 4 + 3], 0.125f, -xv.w);
      xrt[f + 0][r] = xv.x;
      xrt[f + 1][r] = xv.y;
      xrt[f + 2][r] = xv.z;
      xrt[f + 3][r] = xv.w;
    }
  }
  __syncthreads();

  {  // matvec: thread (r, oc) computes 16 outputs of row r0+r
    const int r = tid & 63, oc = tid >> 6;
    float acc[16];
#pragma unroll
    for (int j = 0; j < 16; ++j) acc[j] = cb[oc * 16 + j];
#pragma unroll 4
    for (int f = 0; f < 64; ++f) {
      const float mv = mdt[f][r];   // conflict-free vector read
      const float xv = xrt[f][r];
      const float4* w4 = (const float4*)(&wtd[f][oc * 16]);  // broadcast b128
      const float4* v4 = (const float4*)(&wts[f][oc * 16]);
#pragma unroll
      for (int q = 0; q < 4; ++q) {
        const float4 a = w4[q], bb = v4[q];
        acc[q * 4 + 0] = fmaf(a.x, mv, fmaf(bb.x, xv, acc[q * 4 + 0]));
        acc[q * 4 + 1] = fmaf(a.y, mv, fmaf(bb.y, xv, acc[q * 4 + 1]));
        acc[q * 4 + 2] = fmaf(a.z, mv, fmaf(bb.z, xv, acc[q * 4 + 2]));
        acc[q * 4 + 3] = fmaf(a.w, mv, fmaf(bb.w, xv, acc[q * 4 + 3]));
      }
    }
    const int row = r0 + r;
    float* op = out + (size_t)b * OCH * NPT + row;
#pragma unroll
    for (int j = 0; j < 16; ++j) op[(oc * 16 + j) * NPT] = acc[j];  // coalesced over r
  }
}

extern "C" void kernel_launch(void* const* d_in, const int* in_sizes, int n_in,
                              void* d_out, int out_size, void* d_ws, size_t ws_size,
                              hipStream_t stream) {
  const float* x    = (const float*)d_in[0];
  const float* Wd   = (const float*)d_in[1];
  const float* bd   = (const float*)d_in[2];
  const float* Ws   = (const float*)d_in[3];
  const float* bs   = (const float*)d_in[4];
  const float* bias = (const float*)d_in[5];
  // d_in[6] is k == 8, hardcoded (register top-k requires compile-time k)
  float* out = (float*)d_out;

  float* xt  = (float*)d_ws;                          // 2,097,152 floats
  float* sqw = xt + (size_t)BATCH * NPT * FDIM;       //    32,768 floats
  int*   nbr = (int*)(sqw + (size_t)BATCH * NPT);     //   262,144 ints

  k_prep<<<dim3(BATCH * 16), dim3(256), 0, stream>>>(x, xt, sqw);
  k_knn <<<dim3(BATCH * 16), dim3(256), 0, stream>>>(xt, sqw, nbr);
  k_out <<<dim3(BATCH * 16), dim3(256), 0, stream>>>(xt, nbr, Wd, bd, Ws, bs, bias, out);
}